// Round 7
// baseline (338.765 us; speedup 1.0000x reference)
//
#include <hip/hip_runtime.h>
#include <hip/hip_bf16.h>
#include <stdint.h>

#define EMB 1024
#define NH 16
#define HD 64
#define SEQ 2048
#define NB 4

typedef __attribute__((ext_vector_type(8))) short bh8;
typedef __attribute__((ext_vector_type(4))) float f32x4;

// attn softmax: scores pre-scaled into log2 domain (0.125*log2e folded into Q),
// static normalization constant M=48 folded into the QK^T MFMA C-init.
#define QSCALE 0.1803368801111f   // 0.125 * log2(e)
#define SMAX_NEG -48.0f

__device__ __forceinline__ unsigned short f2bf(float x) {
  union { float f; uint32_t u; } v; v.f = x;
  uint32_t r = v.u + 0x7FFFu + ((v.u >> 16) & 1u);
  return (unsigned short)(r >> 16);
}

__device__ __forceinline__ void async16(void* lds, const void* g) {
  __builtin_amdgcn_global_load_lds(
      (const __attribute__((address_space(1))) uint32_t*)g,
      (__attribute__((address_space(3))) uint32_t*)lds,
      16, 0, 0);
}

#define MFMA_BF16(a, b, c) __builtin_amdgcn_mfma_f32_16x16x32_bf16((a), (b), (c), 0, 0, 0)

// ---------------- LayerNorm: fp32 x -> bf16 h ----------------
__global__ __launch_bounds__(256) void ln_kernel(const float* __restrict__ x,
                                                 const float* __restrict__ gamma,
                                                 const float* __restrict__ beta,
                                                 unsigned short* __restrict__ hout) {
  const int row = blockIdx.x;
  const int t = threadIdx.x;
  const float4 xv = ((const float4*)(x + (size_t)row * EMB))[t];
  float s = xv.x + xv.y + xv.z + xv.w;
  float ss = xv.x * xv.x + xv.y * xv.y + xv.z * xv.z + xv.w * xv.w;
#pragma unroll
  for (int off = 32; off; off >>= 1) {
    s += __shfl_down(s, off);
    ss += __shfl_down(ss, off);
  }
  __shared__ float red[8];
  const int wid = t >> 6, lane = t & 63;
  if (lane == 0) { red[wid] = s; red[4 + wid] = ss; }
  __syncthreads();
  const float S = red[0] + red[1] + red[2] + red[3];
  const float SS = red[4] + red[5] + red[6] + red[7];
  const float mu = S * (1.0f / EMB);
  const float var = SS * (1.0f / EMB) - mu * mu;
  const float rstd = rsqrtf(var + 1e-5f);
  const float4 gv = ((const float4*)gamma)[t];
  const float4 bv = ((const float4*)beta)[t];
  ushort4 o = make_ushort4(f2bf((xv.x - mu) * rstd * gv.x + bv.x),
                           f2bf((xv.y - mu) * rstd * gv.y + bv.y),
                           f2bf((xv.z - mu) * rstd * gv.z + bv.z),
                           f2bf((xv.w - mu) * rstd * gv.w + bv.w));
  ((ushort4*)(hout + (size_t)row * EMB))[t] = o;
}

// ---------------- weight/bias prep: fp32 -> bf16 ----------------
__global__ __launch_bounds__(256) void prep_kernel(const float* __restrict__ Wq, const float* __restrict__ Wk,
                                                   const float* __restrict__ Wv, const float* __restrict__ Wo,
                                                   const float* __restrict__ bq, const float* __restrict__ bk,
                                                   const float* __restrict__ bv,
                                                   unsigned short* __restrict__ wcat,
                                                   unsigned short* __restrict__ wo,
                                                   float* __restrict__ bcat) {
  const int b = blockIdx.x;
  const int t = threadIdx.x;
  if (b < 3072) {  // 3M elems of Wq|Wk|Wv -> wcat [3072][1024]
    const int i = b * 1024 + t * 4;
    const int proj = i >> 20;
    const int rem = i & 0xFFFFF;
    const float* src = (proj == 0) ? Wq : ((proj == 1) ? Wk : Wv);
    const float4 v = *(const float4*)(src + rem);
    *(ushort4*)(wcat + i) = make_ushort4(f2bf(v.x), f2bf(v.y), f2bf(v.z), f2bf(v.w));
  } else if (b < 4096) {  // Wo -> wo
    const int i = (b - 3072) * 1024 + t * 4;
    const float4 v = *(const float4*)(Wo + i);
    *(ushort4*)(wo + i) = make_ushort4(f2bf(v.x), f2bf(v.y), f2bf(v.z), f2bf(v.w));
  } else {  // bias concat (3 blocks * 1024 = 3072 floats)
    const int i = (b - 4096) * 1024 + t * 4;
    const int proj = i >> 10;
    const int rem = i & 1023;
    const float* src = (proj == 0) ? bq : ((proj == 1) ? bk : bv);
    const float4 v = *(const float4*)(src + rem);
    *(float4*)(bcat + i) = v;
  }
}

// ---------------- bf16 GEMM  C[M][N] = A[M][K] * B[N][K]^T  (m97 structure) ----------------
// MFMA operands are SWAPPED (mfma(b,a)): the output fragment is C^T-mapped, i.e.
// each thread holds 4 CONSECUTIVE n-columns (reg index) x 1 m-row (lane&15) ->
// vectorized ushort4/float4 epilogue stores (4x fewer store+cvt instructions).
// EPI==0: out = bf16 scatter into qkv[(proj, b*16+h, s, d)] with bias (N=3072 layout);
//         Q (proj 0) additionally scaled by QSCALE (attn softmax scale folded in).
// EPI==1: out = fp32 [M][N] with bias + residual
template <int EPI>
__global__ __launch_bounds__(256) void gemm_bt(const unsigned short* __restrict__ A,
                                               const unsigned short* __restrict__ B,
                                               int M, int N, int K, int mtiles,
                                               const float* __restrict__ bias,
                                               const float* __restrict__ resid,
                                               unsigned short* __restrict__ outq,
                                               float* __restrict__ outf) {
  __shared__ unsigned short Asm_[128 * 32];
  __shared__ unsigned short Bsm_[128 * 32];
  const int mt = blockIdx.x % mtiles;
  const int nt = blockIdx.x / mtiles;
  const int m0 = mt * 128, n0 = nt * 128;
  const int t = threadIdx.x;
  const int w = t >> 6, l = t & 63;
  const int wr = w >> 1, wc = w & 1;  // 2x2 wave grid, each wave 64x64
  const int rlo = l & 15, rhi = l >> 4;

  f32x4 acc[4][4] = {};

  const int srow = (l >> 2);          // 0..15 within chunk
  const int scol = (l & 3) * 8;       // k element offset

  for (int k0 = 0; k0 < K; k0 += 32) {
#pragma unroll
    for (int cc = 0; cc < 2; ++cc) {
      const int c = 2 * w + cc;
      const int row = c * 16 + srow;
      async16(&Asm_[c * 512 + l * 8], &A[(size_t)(m0 + row) * K + k0 + scol]);
      async16(&Bsm_[c * 512 + l * 8], &B[(size_t)(n0 + row) * K + k0 + scol]);
    }
    __syncthreads();
    bh8 af[4], bfr[4];
#pragma unroll
    for (int i = 0; i < 4; ++i)
      af[i] = *(const bh8*)&Asm_[(wr * 64 + i * 16 + rlo) * 32 + rhi * 8];
#pragma unroll
    for (int i = 0; i < 4; ++i)
      bfr[i] = *(const bh8*)&Bsm_[(wc * 64 + i * 16 + rlo) * 32 + rhi * 8];
#pragma unroll
    for (int i = 0; i < 4; ++i)
#pragma unroll
      for (int j = 0; j < 4; ++j)
        acc[i][j] = MFMA_BF16(bfr[j], af[i], acc[i][j]);  // swapped: C^T fragment
    __syncthreads();
  }

  // Epilogue: acc[i][j][r] = C[m0+wr*64+i*16+rlo][n0+wc*64+j*16+rhi*4+r]
#pragma unroll
  for (int j = 0; j < 4; ++j) {
    const int ncb = n0 + wc * 64 + j * 16 + rhi * 4;  // 4-aligned col base
    const float4 bv4 = *(const float4*)&bias[ncb];
#pragma unroll
    for (int i = 0; i < 4; ++i) {
      const int row = m0 + wr * 64 + i * 16 + rlo;
      float v0 = acc[i][j][0] + bv4.x;
      float v1 = acc[i][j][1] + bv4.y;
      float v2 = acc[i][j][2] + bv4.z;
      float v3 = acc[i][j][3] + bv4.w;
      if (EPI == 0) {
        const int proj = ncb >> 10;
        if (proj == 0) { v0 *= QSCALE; v1 *= QSCALE; v2 *= QSCALE; v3 *= QSCALE; }
        const int rem = ncb & 1023;
        const int hh = rem >> 6, d = rem & 63;  // 4 consecutive d within one head
        const int bb = row >> 11, ss = row & 2047;
        const ushort4 pk = make_ushort4(f2bf(v0), f2bf(v1), f2bf(v2), f2bf(v3));
        *(ushort4*)&outq[(size_t)proj * 8388608 + (((size_t)(bb * 16 + hh) * 2048 + ss) << 6) + d] = pk;
      } else {
        const size_t idx = (size_t)row * N + ncb;
        const float4 rv = *(const float4*)&resid[idx];
        *(float4*)&outf[idx] = make_float4(v0 + rv.x, v1 + rv.y, v2 + rv.z, v3 + rv.w);
      }
    }
  }
}

// ---------------- flash attention (bf16 MFMA, static-max softmax, 2-phase prefetch) ----
// Q/K/V: [64 bh][2048][64] bf16 (Q pre-scaled by 0.125*log2e).  Out: [8192][1024] bf16.
// Block = 128 q-rows (wave = 32 q as two 16-row groups); KV tile = 64 keys.
// Key-axis permutation kappa(key) = 4*(key&15) + (key>>4) shared by P and Vsm.
// Per-wave P buffer is 16 rows, reused by the two q-groups sequentially (in-wave
// DS ordering makes the reuse safe) -> LDS 40 KB -> 4 blocks/CU (grid 1024 = 4/CU).
__device__ __forceinline__ void stage_k(const unsigned short* __restrict__ Kb, size_t base,
                                        int kt, unsigned short* Ksm, int w, int l) {
#pragma unroll
  for (int cc = 0; cc < 2; ++cc) {
    const int c = 2 * w + cc;
    const int key = c * 8 + (l >> 3);
    const int colb = ((l & 7) * 16) ^ ((key & 7) << 4);
    async16(&((char*)Ksm)[c * 1024 + l * 16],
            (const char*)&Kb[base + (size_t)(kt * 64 + key) * HD] + colb);
  }
}

// V staging, kappa-keyed: thread handles kappa-pair m = t&31 (physical keys
// k0 = 32*(m&1) + (m>>1) and k0+16) x d-octet voct = t>>5.
__device__ __forceinline__ void load_v(const unsigned short* __restrict__ Vb, size_t base,
                                       int kt, int m, int voct, bh8* v0, bh8* v1) {
  const int k0 = ((m & 1) << 5) + (m >> 1);
  const unsigned short* vsrc = &Vb[base + (size_t)(kt * 64 + k0) * HD + voct * 8];
  *v0 = *(const bh8*)vsrc;             // kappa = 2m   (low half of pair)
  *v1 = *(const bh8*)(vsrc + 16 * HD); // kappa = 2m+1 (high half)
}

// write transposed+swizzled: u32 pair m of row d at index d*32 + (m ^ ((d&7)<<2)).
__device__ __forceinline__ void write_v(unsigned short* Vsm, int m, int voct, bh8 v0, bh8 v1) {
  uint32_t* V32 = (uint32_t*)Vsm;
#pragma unroll
  for (int i = 0; i < 8; ++i) {
    const int d = voct * 8 + i;
    const uint32_t pk = (uint32_t)(unsigned short)v0[i] | ((uint32_t)(unsigned short)v1[i] << 16);
    V32[d * 32 + (m ^ ((d & 7) << 2))] = pk;
  }
}

__global__ __launch_bounds__(256) void attn_kernel(const unsigned short* __restrict__ Qb,
                                                   const unsigned short* __restrict__ Kb,
                                                   const unsigned short* __restrict__ Vb,
                                                   unsigned short* __restrict__ Ob) {
  __shared__ unsigned short Ksm[2][64 * 64];   // [key][d], XOR-swizzled, double-buffered
  __shared__ unsigned short Vsm[2][64 * 64];   // [d][kappa] transposed, swizzled, double-buffered
  __shared__ unsigned short Psm[4][16 * 64];   // per-wave P buffer [q][kappa], swizzled, reused per group

  // XCD-aware chunked swizzle (T1): 1024 blocks -> 128 logical per XCD (8 heads' worth).
  const int lb = ((blockIdx.x & 7) << 7) | (blockIdx.x >> 3);
  const int qt = lb & 15;
  const int bh = lb >> 4;
  const int t = threadIdx.x, w = t >> 6, l = t & 63;
  const int rlo = l & 15, rhi = l >> 4;
  const int q0 = qt * 128 + w * 32;
  const size_t base = (size_t)bh * SEQ * HD;

  // Q fragments: two 16-row groups g, row = q0 + g*16 + rlo, k = ds*32 + rhi*8
  bh8 qa[2][2];
#pragma unroll
  for (int g = 0; g < 2; ++g)
#pragma unroll
    for (int ds = 0; ds < 2; ++ds)
      qa[g][ds] = *(const bh8*)&Qb[base + (size_t)(q0 + g * 16 + rlo) * HD + ds * 32 + rhi * 8];

  f32x4 o[2][4] = {};
  float psum[2][4] = {};

  const int vm = t & 31;    // kappa pair id
  const int voct = t >> 5;  // d octet

  // --- prologue: stage tile 0 into buffer 0 ---
  stage_k(Kb, base, 0, Ksm[0], w, l);
  {
    bh8 v0, v1;
    load_v(Vb, base, 0, vm, voct, &v0, &v1);
    write_v(Vsm[0], vm, voct, v0, v1);
  }
  __syncthreads();

  for (int kt = 0; kt < 32; ++kt) {
    const int cur = kt & 1;
    bh8 nv0, nv1;
    // --- prefetch next tile (issues only; drained by end-of-iter barrier) ---
    if (kt < 31) {
      stage_k(Kb, base, kt + 1, Ksm[cur ^ 1], w, l);
      load_v(Vb, base, kt + 1, vm, voct, &nv0, &nv1);
    }

    // --- QK^T: scores [32q][64k]; C-init = -48; each K-frag read once, used 2x ---
    const unsigned short* Kc = Ksm[cur];
    f32x4 sc[2][4];
#pragma unroll
    for (int kb = 0; kb < 4; ++kb) {
      sc[0][kb] = f32x4{SMAX_NEG, SMAX_NEG, SMAX_NEG, SMAX_NEG};
      sc[1][kb] = f32x4{SMAX_NEG, SMAX_NEG, SMAX_NEG, SMAX_NEG};
    }
#pragma unroll
    for (int kb = 0; kb < 4; ++kb) {
      const int key = kb * 16 + rlo;
#pragma unroll
      for (int ds = 0; ds < 2; ++ds) {
        const int colb = (ds * 64 + rhi * 16) ^ ((key & 7) << 4);
        const bh8 kf = *(const bh8*)&((const char*)Kc)[key * 128 + colb];
        sc[0][kb] = MFMA_BF16(qa[0][ds], kf, sc[0][kb]);
        sc[1][kb] = MFMA_BF16(qa[1][ds], kf, sc[1][kb]);
      }
    }

    // --- per group: static-max softmax, kappa-packed P write (b64), pa read ---
    uint32_t* P32 = (uint32_t*)Psm[w];
    const unsigned short* Pw = (const unsigned short*)Psm[w];
    bh8 pa[2][2];
#pragma unroll
    for (int g = 0; g < 2; ++g) {
#pragma unroll
      for (int kb = 0; kb < 4; ++kb)
#pragma unroll
        for (int r = 0; r < 4; ++r) {
          const float p = __builtin_amdgcn_exp2f(sc[g][kb][r]);
          sc[g][kb][r] = p;
          psum[g][r] += p;
        }
#pragma unroll
      for (int r = 0; r < 4; ++r) {
        const int q = rhi * 4 + r;                 // row within the 16-row buffer
        const int e = (2 * rlo) ^ ((q & 7) << 2);  // even dword; pair (e, e+1)
        union { __hip_bfloat162 b; uint32_t u; } p0, p1;
        p0.b = __float22bfloat162_rn(make_float2(sc[g][0][r], sc[g][1][r]));  // kappa 4rlo..+1
        p1.b = __float22bfloat162_rn(make_float2(sc[g][2][r], sc[g][3][r]));  // kappa 4rlo+2..+3
        *(uint2*)((char*)P32 + q * 128 + e * 4) = make_uint2(p0.u, p1.u);
      }
#pragma unroll
      for (int ks = 0; ks < 2; ++ks) {
        const int colb = (ks * 64 + rhi * 16) ^ ((rlo & 7) << 4);
        pa[g][ks] = *(const bh8*)&((const char*)Pw)[rlo * 128 + colb];
      }
    }

    // --- PV: O += P * V; each V-frag read once, used 2x ---
    const unsigned short* Vc = Vsm[cur];
#pragma unroll
    for (int ks = 0; ks < 2; ++ks)
#pragma unroll
      for (int df = 0; df < 4; ++df) {
        const int d = df * 16 + rlo;
        const int colb = (ks * 64 + rhi * 16) ^ ((d & 7) << 4);
        const bh8 vf = *(const bh8*)&((const char*)Vc)[d * 128 + colb];
        o[0][df] = MFMA_BF16(pa[0][ks], vf, o[0][df]);
        o[1][df] = MFMA_BF16(pa[1][ks], vf, o[1][df]);
      }

    // --- write prefetched V into next buffer (after PV so global loads had max cover) ---
    if (kt < 31) write_v(Vsm[cur ^ 1], vm, voct, nv0, nv1);

    __syncthreads();  // drains K-async (vmcnt) + V ds_writes (lgkm); frees buffers
  }

  // --- one-time sum reduce across the 16 key-lanes ---
#pragma unroll
  for (int g = 0; g < 2; ++g)
#pragma unroll
    for (int r = 0; r < 4; ++r) {
#pragma unroll
      for (int off = 1; off < 16; off <<= 1) psum[g][r] += __shfl_xor(psum[g][r], off);
    }

  // --- epilogue: normalize, write (B,S,E) bf16 ---
  const size_t brow = (size_t)(bh >> 4) * SEQ;
  const int hcol = (bh & 15) * HD;
#pragma unroll
  for (int g = 0; g < 2; ++g)
#pragma unroll
    for (int r = 0; r < 4; ++r) {
      const float inv = 1.0f / psum[g][r];
      const int q = q0 + g * 16 + rhi * 4 + r;
#pragma unroll
      for (int df = 0; df < 4; ++df)
        Ob[(brow + q) * EMB + hcol + df * 16 + rlo] = f2bf(o[g][df][r] * inv);
    }
}

extern "C" void kernel_launch(void* const* d_in, const int* in_sizes, int n_in,
                              void* d_out, int out_size, void* d_ws, size_t ws_size,
                              hipStream_t stream) {
  const float* x = (const float*)d_in[0];
  const float* Wq = (const float*)d_in[1];
  const float* bq = (const float*)d_in[2];
  const float* Wk = (const float*)d_in[3];
  const float* bk = (const float*)d_in[4];
  const float* Wv = (const float*)d_in[5];
  const float* bv = (const float*)d_in[6];
  const float* Wo = (const float*)d_in[7];
  const float* bo = (const float*)d_in[8];
  const float* gamma = (const float*)d_in[9];
  const float* beta = (const float*)d_in[10];

  // workspace layout (73 MB total):
  //   [0,16M)   h   (bf16 LN output)  -- dead after QKV GEMM, reused as aout
  //   [16,22M)  wcat (bf16 Wq|Wk|Wv)
  //   [22,24M)  wo   (bf16 Wo)
  //   [24,25M)  bcat (fp32 bq|bk|bv)
  //   [25,73M)  qkv  (bf16 [3][64][2048][64])
  char* ws = (char*)d_ws;
  unsigned short* h = (unsigned short*)(ws);
  unsigned short* wcat = (unsigned short*)(ws + (16u << 20));
  unsigned short* wo = (unsigned short*)(ws + (22u << 20));
  float* bcat = (float*)(ws + (24u << 20));
  unsigned short* qkv = (unsigned short*)(ws + (25u << 20));
  unsigned short* aout = h;  // alias: h dead once attention runs
  float* out = (float*)d_out;

  ln_kernel<<<dim3(8192), dim3(256), 0, stream>>>(x, gamma, beta, h);
  prep_kernel<<<dim3(4099), dim3(256), 0, stream>>>(Wq, Wk, Wv, Wo, bq, bk, bv, wcat, wo, bcat);
  gemm_bt<0><<<dim3(64 * 24), dim3(256), 0, stream>>>(h, wcat, 8192, 3072, 1024, 64,
                                                      bcat, nullptr, qkv, nullptr);
  attn_kernel<<<dim3(1024), dim3(256), 0, stream>>>(qkv, qkv + 8388608, qkv + 16777216, aout);
  gemm_bt<1><<<dim3(64 * 8), dim3(256), 0, stream>>>(aout, wo, 8192, 1024, 1024, 64,
                                                     bo, x, nullptr, out);
}

// Round 9
// 333.190 us; speedup vs baseline: 1.0167x; 1.0167x over previous
//
#include <hip/hip_runtime.h>
#include <hip/hip_bf16.h>
#include <stdint.h>

#define EMB 1024
#define NH 16
#define HD 64
#define SEQ 2048
#define NB 4

typedef __attribute__((ext_vector_type(8))) short bh8;
typedef __attribute__((ext_vector_type(4))) float f32x4;

// attn softmax: scores pre-scaled into log2 domain (0.125*log2e folded into Q),
// static normalization constant M=48 folded into the QK^T MFMA C-init.
#define QSCALE 0.1803368801111f   // 0.125 * log2(e)
#define SMAX_NEG -48.0f

__device__ __forceinline__ unsigned short f2bf(float x) {
  union { float f; uint32_t u; } v; v.f = x;
  uint32_t r = v.u + 0x7FFFu + ((v.u >> 16) & 1u);
  return (unsigned short)(r >> 16);
}

__device__ __forceinline__ void async16(void* lds, const void* g) {
  __builtin_amdgcn_global_load_lds(
      (const __attribute__((address_space(1))) uint32_t*)g,
      (__attribute__((address_space(3))) uint32_t*)lds,
      16, 0, 0);
}

#define MFMA_BF16(a, b, c) __builtin_amdgcn_mfma_f32_16x16x32_bf16((a), (b), (c), 0, 0, 0)

// ---------------- LayerNorm: fp32 x -> bf16 h ----------------
__global__ __launch_bounds__(256) void ln_kernel(const float* __restrict__ x,
                                                 const float* __restrict__ gamma,
                                                 const float* __restrict__ beta,
                                                 unsigned short* __restrict__ hout) {
  const int row = blockIdx.x;
  const int t = threadIdx.x;
  const float4 xv = ((const float4*)(x + (size_t)row * EMB))[t];
  float s = xv.x + xv.y + xv.z + xv.w;
  float ss = xv.x * xv.x + xv.y * xv.y + xv.z * xv.z + xv.w * xv.w;
#pragma unroll
  for (int off = 32; off; off >>= 1) {
    s += __shfl_down(s, off);
    ss += __shfl_down(ss, off);
  }
  __shared__ float red[8];
  const int wid = t >> 6, lane = t & 63;
  if (lane == 0) { red[wid] = s; red[4 + wid] = ss; }
  __syncthreads();
  const float S = red[0] + red[1] + red[2] + red[3];
  const float SS = red[4] + red[5] + red[6] + red[7];
  const float mu = S * (1.0f / EMB);
  const float var = SS * (1.0f / EMB) - mu * mu;
  const float rstd = rsqrtf(var + 1e-5f);
  const float4 gv = ((const float4*)gamma)[t];
  const float4 bv = ((const float4*)beta)[t];
  ushort4 o = make_ushort4(f2bf((xv.x - mu) * rstd * gv.x + bv.x),
                           f2bf((xv.y - mu) * rstd * gv.y + bv.y),
                           f2bf((xv.z - mu) * rstd * gv.z + bv.z),
                           f2bf((xv.w - mu) * rstd * gv.w + bv.w));
  ((ushort4*)(hout + (size_t)row * EMB))[t] = o;
}

// ---------------- weight/bias prep: fp32 -> bf16 ----------------
__global__ __launch_bounds__(256) void prep_kernel(const float* __restrict__ Wq, const float* __restrict__ Wk,
                                                   const float* __restrict__ Wv, const float* __restrict__ Wo,
                                                   const float* __restrict__ bq, const float* __restrict__ bk,
                                                   const float* __restrict__ bv,
                                                   unsigned short* __restrict__ wcat,
                                                   unsigned short* __restrict__ wo,
                                                   float* __restrict__ bcat) {
  const int b = blockIdx.x;
  const int t = threadIdx.x;
  if (b < 3072) {  // 3M elems of Wq|Wk|Wv -> wcat [3072][1024]
    const int i = b * 1024 + t * 4;
    const int proj = i >> 20;
    const int rem = i & 0xFFFFF;
    const float* src = (proj == 0) ? Wq : ((proj == 1) ? Wk : Wv);
    const float4 v = *(const float4*)(src + rem);
    *(ushort4*)(wcat + i) = make_ushort4(f2bf(v.x), f2bf(v.y), f2bf(v.z), f2bf(v.w));
  } else if (b < 4096) {  // Wo -> wo
    const int i = (b - 3072) * 1024 + t * 4;
    const float4 v = *(const float4*)(Wo + i);
    *(ushort4*)(wo + i) = make_ushort4(f2bf(v.x), f2bf(v.y), f2bf(v.z), f2bf(v.w));
  } else {  // bias concat (3 blocks * 1024 = 3072 floats)
    const int i = (b - 4096) * 1024 + t * 4;
    const int proj = i >> 10;
    const int rem = i & 1023;
    const float* src = (proj == 0) ? bq : ((proj == 1) ? bk : bv);
    const float4 v = *(const float4*)(src + rem);
    *(float4*)(bcat + i) = v;
  }
}

// ---------------- bf16 GEMM  C[M][N] = A[M][K] * B[N][K]^T  (m97 structure) ----------------
// MFMA operands are SWAPPED (mfma(b,a)): each thread holds 4 CONSECUTIVE n-columns
// -> vectorized ushort4/float4 epilogue stores.
// EPI==0: out = bf16 scatter into qkv[(proj, b*16+h, s, d)] with bias (N=3072 layout);
//         Q (proj 0) additionally scaled by QSCALE (attn softmax scale folded in).
// EPI==1: out = fp32 [M][N] with bias + residual
template <int EPI>
__global__ __launch_bounds__(256) void gemm_bt(const unsigned short* __restrict__ A,
                                               const unsigned short* __restrict__ B,
                                               int M, int N, int K, int mtiles,
                                               const float* __restrict__ bias,
                                               const float* __restrict__ resid,
                                               unsigned short* __restrict__ outq,
                                               float* __restrict__ outf) {
  __shared__ unsigned short Asm_[128 * 32];
  __shared__ unsigned short Bsm_[128 * 32];
  const int mt = blockIdx.x % mtiles;
  const int nt = blockIdx.x / mtiles;
  const int m0 = mt * 128, n0 = nt * 128;
  const int t = threadIdx.x;
  const int w = t >> 6, l = t & 63;
  const int wr = w >> 1, wc = w & 1;  // 2x2 wave grid, each wave 64x64
  const int rlo = l & 15, rhi = l >> 4;

  f32x4 acc[4][4] = {};

  const int srow = (l >> 2);          // 0..15 within chunk
  const int scol = (l & 3) * 8;       // k element offset

  for (int k0 = 0; k0 < K; k0 += 32) {
#pragma unroll
    for (int cc = 0; cc < 2; ++cc) {
      const int c = 2 * w + cc;
      const int row = c * 16 + srow;
      async16(&Asm_[c * 512 + l * 8], &A[(size_t)(m0 + row) * K + k0 + scol]);
      async16(&Bsm_[c * 512 + l * 8], &B[(size_t)(n0 + row) * K + k0 + scol]);
    }
    __syncthreads();
    bh8 af[4], bfr[4];
#pragma unroll
    for (int i = 0; i < 4; ++i)
      af[i] = *(const bh8*)&Asm_[(wr * 64 + i * 16 + rlo) * 32 + rhi * 8];
#pragma unroll
    for (int i = 0; i < 4; ++i)
      bfr[i] = *(const bh8*)&Bsm_[(wc * 64 + i * 16 + rlo) * 32 + rhi * 8];
#pragma unroll
    for (int i = 0; i < 4; ++i)
#pragma unroll
      for (int j = 0; j < 4; ++j)
        acc[i][j] = MFMA_BF16(bfr[j], af[i], acc[i][j]);  // swapped: C^T fragment
    __syncthreads();
  }

  // Epilogue: acc[i][j][r] = C[m0+wr*64+i*16+rlo][n0+wc*64+j*16+rhi*4+r]
#pragma unroll
  for (int j = 0; j < 4; ++j) {
    const int ncb = n0 + wc * 64 + j * 16 + rhi * 4;  // 4-aligned col base
    const float4 bv4 = *(const float4*)&bias[ncb];
#pragma unroll
    for (int i = 0; i < 4; ++i) {
      const int row = m0 + wr * 64 + i * 16 + rlo;
      float v0 = acc[i][j][0] + bv4.x;
      float v1 = acc[i][j][1] + bv4.y;
      float v2 = acc[i][j][2] + bv4.z;
      float v3 = acc[i][j][3] + bv4.w;
      if (EPI == 0) {
        const int proj = ncb >> 10;
        if (proj == 0) { v0 *= QSCALE; v1 *= QSCALE; v2 *= QSCALE; v3 *= QSCALE; }
        const int rem = ncb & 1023;
        const int hh = rem >> 6, d = rem & 63;  // 4 consecutive d within one head
        const int bb = row >> 11, ss = row & 2047;
        const ushort4 pk = make_ushort4(f2bf(v0), f2bf(v1), f2bf(v2), f2bf(v3));
        *(ushort4*)&outq[(size_t)proj * 8388608 + (((size_t)(bb * 16 + hh) * 2048 + ss) << 6) + d] = pk;
      } else {
        const size_t idx = (size_t)row * N + ncb;
        const float4 rv = *(const float4*)&resid[idx];
        *(float4*)&outf[idx] = make_float4(v0 + rv.x, v1 + rv.y, v2 + rv.z, v3 + rv.w);
      }
    }
  }
}

// ---------------- flash attention (bf16 MFMA, static-max softmax, swapped QK^T) ----
// Q/K/V: [64 bh][2048][64] bf16 (Q pre-scaled by 0.125*log2e).  Out: [8192][1024] bf16.
// Block = 128 q-rows (wave = 32 q as two 16-row groups); KV tile = 64 keys.
// SWAPPED QK^T (mfma(K,Q)): lane holds q = lane&15 and 16 keys -> P is packed
// IN-REGISTER into the PV A-operand (no P LDS buffer at all). Shared key
// permutation kappa(key) = (kb&1)*32 + rhi*8 + (kb>>1)*4 + r applied to Vsm.
// LDS = 32 KB (K dbuf 16K + V dbuf 16K).
__device__ __forceinline__ void stage_k(const unsigned short* __restrict__ Kb, size_t base,
                                        int kt, unsigned short* Ksm, int w, int l) {
#pragma unroll
  for (int cc = 0; cc < 2; ++cc) {
    const int c = 2 * w + cc;
    const int key = c * 8 + (l >> 3);
    const int colb = ((l & 7) * 16) ^ ((key & 7) << 4);
    async16(&((char*)Ksm)[c * 1024 + l * 16],
            (const char*)&Kb[base + (size_t)(kt * 64 + key) * HD] + colb);
  }
}

// V staging, kappa-keyed: thread m = t&31 handles kappas (2m, 2m+1), which are
// ADJACENT physical keys key0, key0+1 with key0 = (2*((m>>1)&1) + (m>>4))*16
// + ((m>>2)&3)*4 + 2*(m&1); d-octet voct = t>>5.
__device__ __forceinline__ void load_v(const unsigned short* __restrict__ Vb, size_t base,
                                       int kt, int m, int voct, bh8* v0, bh8* v1) {
  const int key0 = ((((m >> 1) & 1) * 2 + (m >> 4)) << 4) + (((m >> 2) & 3) << 2) + 2 * (m & 1);
  const unsigned short* vsrc = &Vb[base + (size_t)(kt * 64 + key0) * HD + voct * 8];
  *v0 = *(const bh8*)vsrc;        // kappa = 2m
  *v1 = *(const bh8*)(vsrc + HD); // kappa = 2m+1
}

// write transposed+swizzled: u32 pair m of row d at index d*32 + (m ^ ((d&7)<<2)).
__device__ __forceinline__ void write_v(unsigned short* Vsm, int m, int voct, bh8 v0, bh8 v1) {
  uint32_t* V32 = (uint32_t*)Vsm;
#pragma unroll
  for (int i = 0; i < 8; ++i) {
    const int d = voct * 8 + i;
    const uint32_t pk = (uint32_t)(unsigned short)v0[i] | ((uint32_t)(unsigned short)v1[i] << 16);
    V32[d * 32 + (m ^ ((d & 7) << 2))] = pk;
  }
}

__global__ __launch_bounds__(256) void attn_kernel(const unsigned short* __restrict__ Qb,
                                                   const unsigned short* __restrict__ Kb,
                                                   const unsigned short* __restrict__ Vb,
                                                   unsigned short* __restrict__ Ob) {
  __shared__ unsigned short Ksm[2][64 * 64];   // [key][d], XOR-swizzled, double-buffered
  __shared__ unsigned short Vsm[2][64 * 64];   // [d][kappa] transposed, swizzled, double-buffered

  // XCD-aware chunked swizzle (T1): 1024 blocks -> 128 logical per XCD (8 heads' worth).
  const int lb = ((blockIdx.x & 7) << 7) | (blockIdx.x >> 3);
  const int qt = lb & 15;
  const int bh = lb >> 4;
  const int t = threadIdx.x, w = t >> 6, l = t & 63;
  const int rlo = l & 15, rhi = l >> 4;
  const int q0 = qt * 128 + w * 32;
  const size_t base = (size_t)bh * SEQ * HD;

  // Q fragments: two 16-row groups g, row = q0 + g*16 + rlo, k = ds*32 + rhi*8
  bh8 qa[2][2];
#pragma unroll
  for (int g = 0; g < 2; ++g)
#pragma unroll
    for (int ds = 0; ds < 2; ++ds)
      qa[g][ds] = *(const bh8*)&Qb[base + (size_t)(q0 + g * 16 + rlo) * HD + ds * 32 + rhi * 8];

  f32x4 o[2][4] = {};
  float psum[2] = {0.0f, 0.0f};  // per-lane: q = rlo (group g), 16 keys of this lane

  const int vm = t & 31;    // kappa pair id
  const int voct = t >> 5;  // d octet

  // --- prologue: stage tile 0 into buffer 0 ---
  stage_k(Kb, base, 0, Ksm[0], w, l);
  {
    bh8 v0, v1;
    load_v(Vb, base, 0, vm, voct, &v0, &v1);
    write_v(Vsm[0], vm, voct, v0, v1);
  }
  __syncthreads();

  for (int kt = 0; kt < 32; ++kt) {
    const int cur = kt & 1;
    bh8 nv0, nv1;
    // --- prefetch next tile (issues only; drained by end-of-iter barrier) ---
    if (kt < 31) {
      stage_k(Kb, base, kt + 1, Ksm[cur ^ 1], w, l);
      load_v(Vb, base, kt + 1, vm, voct, &nv0, &nv1);
    }

    // --- swapped QK^T: S^T fragments; lane: q=rlo, key=kb*16+rhi*4+r; C-init=-48 ---
    const unsigned short* Kc = Ksm[cur];
    f32x4 sc[2][4];
#pragma unroll
    for (int kb = 0; kb < 4; ++kb) {
      sc[0][kb] = f32x4{SMAX_NEG, SMAX_NEG, SMAX_NEG, SMAX_NEG};
      sc[1][kb] = f32x4{SMAX_NEG, SMAX_NEG, SMAX_NEG, SMAX_NEG};
    }
#pragma unroll
    for (int kb = 0; kb < 4; ++kb) {
      const int key = kb * 16 + rlo;
#pragma unroll
      for (int ds = 0; ds < 2; ++ds) {
        const int colb = (ds * 64 + rhi * 16) ^ ((key & 7) << 4);
        const bh8 kf = *(const bh8*)&((const char*)Kc)[key * 128 + colb];
        sc[0][kb] = MFMA_BF16(kf, qa[0][ds], sc[0][kb]);
        sc[1][kb] = MFMA_BF16(kf, qa[1][ds], sc[1][kb]);
      }
    }

    // --- static-max softmax + IN-REGISTER P pack (kappa = (kb&1)*32 + rhi*8 + (kb>>1)*4 + r) ---
    bh8 pa[2][2];
#pragma unroll
    for (int g = 0; g < 2; ++g) {
      union { bh8 v; uint32_t d[4]; } A0, A1;
      float s_ = 0.0f;
#pragma unroll
      for (int kb = 0; kb < 4; ++kb) {
        const float p0 = __builtin_amdgcn_exp2f(sc[g][kb][0]);
        const float p1 = __builtin_amdgcn_exp2f(sc[g][kb][1]);
        const float p2 = __builtin_amdgcn_exp2f(sc[g][kb][2]);
        const float p3 = __builtin_amdgcn_exp2f(sc[g][kb][3]);
        s_ += (p0 + p1) + (p2 + p3);
        union { __hip_bfloat162 b; uint32_t u; } lo, hi;
        lo.b = __float22bfloat162_rn(make_float2(p0, p1));
        hi.b = __float22bfloat162_rn(make_float2(p2, p3));
        const int dw = (kb >> 1) * 2;  // dword index within ks-half
        if (kb & 1) { A1.d[dw] = lo.u; A1.d[dw + 1] = hi.u; }
        else        { A0.d[dw] = lo.u; A0.d[dw + 1] = hi.u; }
      }
      pa[g][0] = A0.v;
      pa[g][1] = A1.v;
      psum[g] += s_;
    }

    // --- PV: O += P * V; each V-frag read once, used 2x ---
    const unsigned short* Vc = Vsm[cur];
#pragma unroll
    for (int ks = 0; ks < 2; ++ks)
#pragma unroll
      for (int df = 0; df < 4; ++df) {
        const int d = df * 16 + rlo;
        const int colb = (ks * 64 + rhi * 16) ^ ((d & 7) << 4);
        const bh8 vf = *(const bh8*)&((const char*)Vc)[d * 128 + colb];
        o[0][df] = MFMA_BF16(pa[0][ks], vf, o[0][df]);
        o[1][df] = MFMA_BF16(pa[1][ks], vf, o[1][df]);
      }

    // --- write prefetched V into next buffer (after PV so global loads had max cover) ---
    if (kt < 31) write_v(Vsm[cur ^ 1], vm, voct, nv0, nv1);

    __syncthreads();  // drains K-async (vmcnt) + V ds_writes (lgkm); frees buffers
  }

  // --- total per-q sums: butterfly over the 4 rhi groups (lanes same rlo) ---
#pragma unroll
  for (int g = 0; g < 2; ++g) {
    psum[g] += __shfl_xor(psum[g], 16);
    psum[g] += __shfl_xor(psum[g], 32);
  }

  // --- epilogue: normalize, write (B,S,E) bf16; psum[q] fetched from lane q ---
  const size_t brow = (size_t)(bh >> 4) * SEQ;
  const int hcol = (bh & 15) * HD;
#pragma unroll
  for (int g = 0; g < 2; ++g)
#pragma unroll
    for (int r = 0; r < 4; ++r) {
      const float inv = 1.0f / __shfl(psum[g], rhi * 4 + r);
      const int q = q0 + g * 16 + rhi * 4 + r;
#pragma unroll
      for (int df = 0; df < 4; ++df)
        Ob[(brow + q) * EMB + hcol + df * 16 + rlo] = f2bf(o[g][df][r] * inv);
    }
}

extern "C" void kernel_launch(void* const* d_in, const int* in_sizes, int n_in,
                              void* d_out, int out_size, void* d_ws, size_t ws_size,
                              hipStream_t stream) {
  const float* x = (const float*)d_in[0];
  const float* Wq = (const float*)d_in[1];
  const float* bq = (const float*)d_in[2];
  const float* Wk = (const float*)d_in[3];
  const float* bk = (const float*)d_in[4];
  const float* Wv = (const float*)d_in[5];
  const float* bv = (const float*)d_in[6];
  const float* Wo = (const float*)d_in[7];
  const float* bo = (const float*)d_in[8];
  const float* gamma = (const float*)d_in[9];
  const float* beta = (const float*)d_in[10];

  // workspace layout (73 MB total):
  //   [0,16M)   h   (bf16 LN output)  -- dead after QKV GEMM, reused as aout
  //   [16,22M)  wcat (bf16 Wq|Wk|Wv)
  //   [22,24M)  wo   (bf16 Wo)
  //   [24,25M)  bcat (fp32 bq|bk|bv)
  //   [25,73M)  qkv  (bf16 [3][64][2048][64])
  char* ws = (char*)d_ws;
  unsigned short* h = (unsigned short*)(ws);
  unsigned short* wcat = (unsigned short*)(ws + (16u << 20));
  unsigned short* wo = (unsigned short*)(ws + (22u << 20));
  float* bcat = (float*)(ws + (24u << 20));
  unsigned short* qkv = (unsigned short*)(ws + (25u << 20));
  unsigned short* aout = h;  // alias: h dead once attention runs
  float* out = (float*)d_out;

  ln_kernel<<<dim3(8192), dim3(256), 0, stream>>>(x, gamma, beta, h);
  prep_kernel<<<dim3(4099), dim3(256), 0, stream>>>(Wq, Wk, Wv, Wo, bq, bk, bv, wcat, wo, bcat);
  gemm_bt<0><<<dim3(64 * 24), dim3(256), 0, stream>>>(h, wcat, 8192, 3072, 1024, 64,
                                                      bcat, nullptr, qkv, nullptr);
  attn_kernel<<<dim3(1024), dim3(256), 0, stream>>>(qkv, qkv + 8388608, qkv + 16777216, aout);
  gemm_bt<1><<<dim3(64 * 8), dim3(256), 0, stream>>>(aout, wo, 8192, 1024, 1024, 64,
                                                     bo, x, nullptr, out);
}